// Round 2
// baseline (466.799 us; speedup 1.0000x reference)
//
#include <hip/hip_runtime.h>
#include <math.h>

#define B_    32
#define C_IN  12
#define C_HID 16
#define H_    495
#define W_    436
#define HW    (H_ * W_)        // 215820 (even)
#define NPIX  (B_ * HW)        // 6906240
#define NG2   (NPIX / 2)       // 3453120 pixel-pairs

// One thread = 2 consecutive W-pixels. All weight reads use compile-time
// uniform indices on kernel-arg pointers -> scalar loads (SGPR), free as
// v_fma operands. No LDS, no local-array address-taking (SROA-safe).
__global__ __launch_bounds__(256) void temporal_mlp_kernel(
    const float* __restrict__ x,
    const float* __restrict__ w1, const float* __restrict__ b1,
    const float* __restrict__ w2, const float* __restrict__ b2,
    const float* __restrict__ w3, const float* __restrict__ b3,
    float* __restrict__ out)
{
    const int g = blockIdx.x * 256 + threadIdx.x;
    if (g >= NG2) return;

    const int base = g * 2;              // flat pixel index over [B, H*W]
    const int b    = base / HW;          // magic-mul division
    const int p    = base - b * HW;
    const float* xb = x + (size_t)b * (C_IN * HW) + p;

    // 12 coalesced float2 loads (one per input-channel plane), issued
    // back-to-back before any use; normalize folded into one fma each.
    float xn0[12], xn1[12];
    #pragma unroll
    for (int c = 0; c < 12; ++c) {
        float2 t = *(const float2*)(xb + (size_t)c * HW);
        xn0[c] = fmaf(t.x, 1.0f / 255.0f, -0.5f);
        xn1[c] = fmaf(t.y, 1.0f / 255.0f, -0.5f);
    }

    // ---- layer 1: 12 -> 16, relu ----
    float h10[16], h11[16];
    #pragma unroll
    for (int o = 0; o < 16; ++o) {
        const float bb = b1[o];
        float a0 = bb, a1 = bb;
        #pragma unroll
        for (int c = 0; c < 12; ++c) {
            const float w = w1[o * 12 + c];   // scalar load
            a0 = fmaf(xn0[c], w, a0);
            a1 = fmaf(xn1[c], w, a1);
        }
        h10[o] = fmaxf(a0, 0.0f);
        h11[o] = fmaxf(a1, 0.0f);
    }

    // ---- layer 2: 16 -> 16, relu ----
    float h20[16], h21[16];
    #pragma unroll
    for (int o = 0; o < 16; ++o) {
        const float bb = b2[o];
        float a0 = bb, a1 = bb;
        #pragma unroll
        for (int c = 0; c < 16; ++c) {
            const float w = w2[o * 16 + c];   // scalar load
            a0 = fmaf(h10[c], w, a0);
            a1 = fmaf(h11[c], w, a1);
        }
        h20[o] = fmaxf(a0, 0.0f);
        h21[o] = fmaxf(a1, 0.0f);
    }

    // ---- layer 3: 16 -> 1, sigmoid, *255 ----
    float t0 = b3[0], t1 = b3[0];
    #pragma unroll
    for (int c = 0; c < 16; ++c) {
        const float w = w3[c];                // scalar load
        t0 = fmaf(h20[c], w, t0);
        t1 = fmaf(h21[c], w, t1);
    }

    float2 r;
    r.x = 255.0f / (1.0f + expf(-t0));
    r.y = 255.0f / (1.0f + expf(-t1));
    *(float2*)(out + base) = r;
}

extern "C" void kernel_launch(void* const* d_in, const int* in_sizes, int n_in,
                              void* d_out, int out_size, void* d_ws, size_t ws_size,
                              hipStream_t stream) {
    const float* x  = (const float*)d_in[0];
    const float* w1 = (const float*)d_in[1];
    const float* b1 = (const float*)d_in[2];
    const float* w2 = (const float*)d_in[3];
    const float* b2 = (const float*)d_in[4];
    const float* w3 = (const float*)d_in[5];
    const float* b3 = (const float*)d_in[6];
    float* out = (float*)d_out;

    const int grid = (NG2 + 255) / 256;  // 13489 blocks of 256
    temporal_mlp_kernel<<<grid, 256, 0, stream>>>(x, w1, b1, w2, b2, w3, b3, out);
}

// Round 3
// 448.356 us; speedup vs baseline: 1.0411x; 1.0411x over previous
//
#include <hip/hip_runtime.h>
#include <math.h>

#define B_    32
#define C_IN  12
#define C_HID 16
#define H_    495
#define W_    436
#define HW    (H_ * W_)        // 215820 (even)
#define NPIX  (B_ * HW)        // 6906240
#define NG2   (NPIX / 2)       // 3453120 pixel-pairs

typedef float v2f __attribute__((ext_vector_type(2)));

#if __has_builtin(__builtin_elementwise_fma)
static __device__ __forceinline__ v2f pk_fma(v2f a, float w, v2f c) {
    v2f ws = {w, w};
    return __builtin_elementwise_fma(a, ws, c);
}
#else
static __device__ __forceinline__ v2f pk_fma(v2f a, float w, v2f c) {
    v2f r; r.x = fmaf(a.x, w, c.x); r.y = fmaf(a.y, w, c.y); return r;
}
#endif

#if __has_builtin(__builtin_elementwise_max)
static __device__ __forceinline__ v2f pk_relu(v2f a) {
    v2f z = {0.0f, 0.0f};
    return __builtin_elementwise_max(a, z);
}
#else
static __device__ __forceinline__ v2f pk_relu(v2f a) {
    v2f r; r.x = fmaxf(a.x, 0.0f); r.y = fmaxf(a.y, 0.0f); return r;
}
#endif

// One thread = 2 consecutive W-pixels, computed as packed float2 lanes
// (v_pk_fma_f32). Weights staged once to LDS (wave-uniform broadcast reads,
// typed float4 access only — no private-array address punning).
__global__ __launch_bounds__(256) void temporal_mlp_kernel(
    const float* __restrict__ x,
    const float* __restrict__ w1, const float* __restrict__ b1,
    const float* __restrict__ w2, const float* __restrict__ b2,
    const float* __restrict__ w3, const float* __restrict__ b3,
    float* __restrict__ out)
{
    __shared__ __align__(16) float4 sW1[16][3];  // w1 * (1/255): folds x/255
    __shared__ __align__(16) float4 sW2[16][4];
    __shared__ __align__(16) float4 sW3[4];
    __shared__ float sB1[16];                    // b1 - 0.5*rowsum(w1): folds -0.5
    __shared__ float sB2[16];
    __shared__ float sB3;

    const int tid = threadIdx.x;
    {
        float* pW1 = (float*)sW1;
        float* pW2 = (float*)sW2;
        if (tid < 192) pW1[tid] = w1[tid] * (1.0f / 255.0f);
        pW2[tid] = w2[tid];                      // exactly 256 elements
        if (tid < 16) {
            float s = 0.0f;
            #pragma unroll
            for (int c = 0; c < 12; ++c) s += w1[tid * 12 + c];
            sB1[tid] = b1[tid] - 0.5f * s;
            sB2[tid] = b2[tid];
            ((float*)sW3)[tid] = w3[tid];
        }
        if (tid == 0) sB3 = b3[0];
    }
    __syncthreads();

    const int g = blockIdx.x * 256 + tid;
    if (g >= NG2) return;

    const int base = g * 2;                  // flat pixel index over [B, H*W]
    const int b    = base / HW;              // magic-mul division
    const int p    = base - b * HW;
    const float* xb = x + (size_t)b * (C_IN * HW) + p;

    // 12 coalesced float2 loads (one per input-channel plane).
    v2f xn[12];
    #pragma unroll
    for (int c = 0; c < 12; ++c) {
        float2 t = *(const float2*)(xb + (size_t)c * HW);
        v2f v = {t.x, t.y};
        xn[c] = v;
    }

    // ---- layer 1: 12 -> 16, relu (x/255 - 0.5 folded into sW1/sB1) ----
    v2f h1[16];
    #pragma unroll
    for (int o = 0; o < 16; ++o) {
        const float4 wa = sW1[o][0];
        const float4 wb = sW1[o][1];
        const float4 wc = sW1[o][2];
        const float bb = sB1[o];
        v2f a = {bb, bb};
        a = pk_fma(xn[0],  wa.x, a);  a = pk_fma(xn[1],  wa.y, a);
        a = pk_fma(xn[2],  wa.z, a);  a = pk_fma(xn[3],  wa.w, a);
        a = pk_fma(xn[4],  wb.x, a);  a = pk_fma(xn[5],  wb.y, a);
        a = pk_fma(xn[6],  wb.z, a);  a = pk_fma(xn[7],  wb.w, a);
        a = pk_fma(xn[8],  wc.x, a);  a = pk_fma(xn[9],  wc.y, a);
        a = pk_fma(xn[10], wc.z, a);  a = pk_fma(xn[11], wc.w, a);
        h1[o] = pk_relu(a);
    }

    // ---- layer 2: 16 -> 16, relu ----
    v2f h2[16];
    #pragma unroll
    for (int o = 0; o < 16; ++o) {
        const float4 wa = sW2[o][0];
        const float4 wb = sW2[o][1];
        const float4 wc = sW2[o][2];
        const float4 wd = sW2[o][3];
        const float bb = sB2[o];
        v2f a = {bb, bb};
        a = pk_fma(h1[0],  wa.x, a);  a = pk_fma(h1[1],  wa.y, a);
        a = pk_fma(h1[2],  wa.z, a);  a = pk_fma(h1[3],  wa.w, a);
        a = pk_fma(h1[4],  wb.x, a);  a = pk_fma(h1[5],  wb.y, a);
        a = pk_fma(h1[6],  wb.z, a);  a = pk_fma(h1[7],  wb.w, a);
        a = pk_fma(h1[8],  wc.x, a);  a = pk_fma(h1[9],  wc.y, a);
        a = pk_fma(h1[10], wc.z, a);  a = pk_fma(h1[11], wc.w, a);
        a = pk_fma(h1[12], wd.x, a);  a = pk_fma(h1[13], wd.y, a);
        a = pk_fma(h1[14], wd.z, a);  a = pk_fma(h1[15], wd.w, a);
        h2[o] = pk_relu(a);
    }

    // ---- layer 3: 16 -> 1, sigmoid, *255 ----
    const float4 ua = sW3[0];
    const float4 ub = sW3[1];
    const float4 uc = sW3[2];
    const float4 ud = sW3[3];
    const float b3v = sB3;
    v2f t = {b3v, b3v};
    t = pk_fma(h2[0],  ua.x, t);  t = pk_fma(h2[1],  ua.y, t);
    t = pk_fma(h2[2],  ua.z, t);  t = pk_fma(h2[3],  ua.w, t);
    t = pk_fma(h2[4],  ub.x, t);  t = pk_fma(h2[5],  ub.y, t);
    t = pk_fma(h2[6],  ub.z, t);  t = pk_fma(h2[7],  ub.w, t);
    t = pk_fma(h2[8],  uc.x, t);  t = pk_fma(h2[9],  uc.y, t);
    t = pk_fma(h2[10], uc.z, t);  t = pk_fma(h2[11], uc.w, t);
    t = pk_fma(h2[12], ud.x, t);  t = pk_fma(h2[13], ud.y, t);
    t = pk_fma(h2[14], ud.z, t);  t = pk_fma(h2[15], ud.w, t);

    float2 r;
    r.x = 255.0f / (1.0f + __expf(-t.x));
    r.y = 255.0f / (1.0f + __expf(-t.y));
    *(float2*)(out + base) = r;
}

extern "C" void kernel_launch(void* const* d_in, const int* in_sizes, int n_in,
                              void* d_out, int out_size, void* d_ws, size_t ws_size,
                              hipStream_t stream) {
    const float* x  = (const float*)d_in[0];
    const float* w1 = (const float*)d_in[1];
    const float* b1 = (const float*)d_in[2];
    const float* w2 = (const float*)d_in[3];
    const float* b2 = (const float*)d_in[4];
    const float* w3 = (const float*)d_in[5];
    const float* b3 = (const float*)d_in[6];
    float* out = (float*)d_out;

    const int grid = (NG2 + 255) / 256;  // 13489 blocks of 256
    temporal_mlp_kernel<<<grid, 256, 0, stream>>>(x, w1, b1, w2, b2, w3, b3, out);
}